// Round 3
// baseline (543.171 us; speedup 1.0000x reference)
//
#include <hip/hip_runtime.h>
#include <hip/hip_bf16.h>

typedef __hip_bfloat16 bf16;
typedef __bf16 bf8v __attribute__((ext_vector_type(8)));
typedef float f4v __attribute__((ext_vector_type(4)));

// workspace layout (bytes)
#define WS_BIAS   0        // bf16, MFMA-C-layout-permuted [4][4][4][4][16][4] = 32768
#define WS_TABLE  32768    // float[225][4]    = 3600 (padded to 4096)
#define WS_QKVT   36864    // bf16[384][128]   = 98304
#define WS_PROJT  135168   // bf16[128][128]   = 32768

__device__ __forceinline__ float rdf(const void* p, int i, int isbf) {
  return isbf ? __bfloat162float(((const bf16*)p)[i]) : ((const float*)p)[i];
}

// dtype detect: coords[0] == -1.0 exactly. fp32 -1.0 -> low 16 bits 0x0000;
// bf16 -1.0 -> 0xBF80. Each kernel derives this itself (no separate kernel).
__device__ __forceinline__ int dtflag(const void* coords) {
  return (*(const unsigned short*)coords != 0) ? 1 : 0;
}

__global__ void prep_transpose(const void* __restrict__ Wqkv,
                               const void* __restrict__ Wproj,
                               const void* __restrict__ coords,
                               char* __restrict__ ws) {
  int idx = blockIdx.x * 256 + threadIdx.x;   // 65536 threads
  int isbf = dtflag(coords);
  bf16* qt = (bf16*)(ws + WS_QKVT);
  bf16* pt = (bf16*)(ws + WS_PROJT);
  if (idx < 384 * 128) {
    int c = idx >> 7, k = idx & 127;
    qt[idx] = __float2bfloat16(rdf(Wqkv, k * 384 + c, isbf));
  } else {
    int j = idx - 384 * 128;                  // < 16384
    int c = j >> 7, k = j & 127;
    pt[j] = __float2bfloat16(rdf(Wproj, k * 128 + c, isbf));
  }
}

// 225 blocks x 512 threads: one hidden unit per thread, reduce across block.
__global__ void prep_table(const void* __restrict__ coords,
                           const void* __restrict__ w1,
                           const void* __restrict__ b1,
                           const void* __restrict__ w2,
                           const void* __restrict__ hts,
                           const void* __restrict__ pps,
                           const void* __restrict__ ws1,
                           const void* __restrict__ ws2,
                           char* __restrict__ ws) {
  __shared__ float red[8][4];
  const int r = blockIdx.x;       // 0..224
  const int j = threadIdx.x;      // 0..511
  const int isbf = dtflag(coords);
  float* table = (float*)(ws + WS_TABLE);

  float ht  = log1pf(__expf(rdf(hts, 0, isbf)));                 // softplus
  float pp  = 1.f / (1.f + __expf(-rdf(pps, 0, isbf)));          // sigmoid
  float wsv = log1pf(__expf(rdf(ws1, 0, isbf))) /
              log1pf(__expf(rdf(ws2, 0, isbf)));
  float t0 = rdf(coords, 2 * r + 0, isbf) * ht;
  float t1 = rdf(coords, 2 * r + 1, isbf) * ht;
  float s0 = (t0 > 0.f) ? 1.f : ((t0 < 0.f) ? -1.f : 0.f);
  float s1 = (t1 > 0.f) ? 1.f : ((t1 < 0.f) ? -1.f : 0.f);
  float u0 = s0 * __powf(fabsf(t0) + 1e-6f, pp) * wsv;
  float u1 = s1 * __powf(fabsf(t1) + 1e-6f, pp) * wsv;

  float h = u0 * rdf(w1, j, isbf) + u1 * rdf(w1, 512 + j, isbf) + rdf(b1, j, isbf);
  h = fmaxf(h, 0.f);
  float a[4];
#pragma unroll
  for (int q = 0; q < 4; ++q) a[q] = h * rdf(w2, 4 * j + q, isbf);
#pragma unroll
  for (int off = 1; off < 64; off <<= 1)
#pragma unroll
    for (int q = 0; q < 4; ++q) a[q] += __shfl_xor(a[q], off);
  int wv = j >> 6, ln = j & 63;
  if (ln == 0) {
#pragma unroll
    for (int q = 0; q < 4; ++q) red[wv][q] = a[q];
  }
  __syncthreads();
  if (j < 4) {
    float s = 0.f;
#pragma unroll
    for (int w8 = 0; w8 < 8; ++w8) s += red[w8][j];
    table[r * 4 + j] = s;
  }
}

// Permute bias into exact MFMA C-layout order:
//   elem = h*4096 + mt*1024 + n4*256 + quad*64 + l16*4 + r
// so wattn_main reads one uint2 (4 bf16, r=0..3) per (mt, n4).
__global__ void prep_gather(const int* __restrict__ rel, char* __restrict__ ws) {
  int pos = blockIdx.x * 256 + threadIdx.x;   // 4096
  const float* table = (const float*)(ws + WS_TABLE);
  bf16* bias = (bf16*)(ws + WS_BIAS);
  int h = pos >> 10, rest = pos & 1023;
  int mt = rest >> 8, n4 = (rest >> 6) & 3, quad = (rest >> 4) & 3, l16 = rest & 15;
  int jj = n4 * 16 + l16;
  union { uint2 u; bf16 hh[4]; } pk;
#pragma unroll
  for (int r = 0; r < 4; ++r) {
    int i = mt * 16 + quad * 4 + r;
    int rr = rel[i * 64 + jj];
    pk.hh[r] = __float2bfloat16(table[rr * 4 + h]);
  }
  *(uint2*)(bias + pos * 4) = pk.u;
}

// One block per window; wave w == head h. LDS = 20,480 B -> 8 blocks/CU (100%).
//   [0, 16384)      xls : x tile bf16 [64][128], XOR-swizzled byte^=(row&7)<<4
//                   -> reused as os [64][128] (same swizzle)
//                   -> reused as fp32 epilogue staging [32][128], byte^=(row&7)<<4
//   [16384, 20480)  per-wave stripe [16][32] bf16 (64 B rows), 1024 B each,
//                   XOR-swizzled byte^=((row>>1)&3)<<4.  V and P transposes run
//                   as two half-passes (by k2); Q/K single-pass as before.
// __launch_bounds__(256,8): VGPR cap 64 (natural 56 fits; watch for spills).
__global__ __launch_bounds__(256, 8) void wattn_main(
    const void* __restrict__ xp,
    const char* __restrict__ ws,
    const void* __restrict__ bprojp,
    const void* __restrict__ coords,
    void* __restrict__ outp) {
  __shared__ alignas(16) char smem[20480];
  char* smc = smem;
  const int tid  = threadIdx.x;
  const int w    = tid >> 6;
  const int lane = tid & 63;
  const int l16  = lane & 15;
  const int quad = lane >> 4;
  char* sb = smc + 16384 + w * 1024;          // per-wave stripe base
  const int sswz = ((l16 >> 1) & 3) << 4;     // stripe read-swizzle (row = l16)
  const int rsw  = (l16 & 7) << 4;            // xls read-swizzle (row = mt*16+l16)

  const int isbf = dtflag(coords);
  const bf16* WqkvT  = (const bf16*)(ws + WS_QKVT);
  const bf16* WprojT = (const bf16*)(ws + WS_PROJT);
  const bf16* biasg  = (const bf16*)(ws + WS_BIAS);

  const int b = blockIdx.x;

  // ---- stage x -> LDS (bf16 [64][128] swizzled) ----
  if (isbf) {
    const bf16* xb = (const bf16*)xp + (size_t)b * 8192;
#pragma unroll
    for (int it = 0; it < 4; ++it) {
      int e = (tid + it * 256) * 8;
      int row = e >> 7, colb = (e & 127) * 2;
      *(uint4*)(smc + row * 256 + (colb ^ ((row & 7) << 4))) = *(const uint4*)(xb + e);
    }
  } else {
    const float* xb = (const float*)xp + (size_t)b * 8192;
#pragma unroll
    for (int it = 0; it < 4; ++it) {
      int e = (tid + it * 256) * 8;
      int row = e >> 7, colb = (e & 127) * 2;
      f4v a = *(const f4v*)(xb + e);
      f4v c = *(const f4v*)(xb + e + 4);
      union { uint4 u; bf16 h[8]; } pk;
#pragma unroll
      for (int jj = 0; jj < 4; ++jj) {
        pk.h[jj]     = __float2bfloat16(a[jj]);
        pk.h[4 + jj] = __float2bfloat16(c[jj]);
      }
      *(uint4*)(smc + row * 256 + (colb ^ ((row & 7) << 4))) = pk.u;
    }
  }
  __syncthreads();

  const f4v zf = {0.f, 0.f, 0.f, 0.f};
  bf8v vf[2][2], qf[4], kf[4];

  auto run_qkv = [&](int colbase, f4v (&acc)[4][2]) {
    const bf16* Bb = WqkvT + (size_t)colbase * 128;
#pragma unroll
    for (int ks = 0; ks < 4; ++ks) {
      bf8v xk[4];
#pragma unroll
      for (int mt = 0; mt < 4; ++mt)
        xk[mt] = *(const bf8v*)(smc + (mt * 16 + l16) * 256 + ((ks * 64 + quad * 16) ^ rsw));
#pragma unroll
      for (int nt = 0; nt < 2; ++nt) {
        bf8v bfr = *(const bf8v*)(Bb + (nt * 16 + l16) * 128 + ks * 32 + quad * 8);
#pragma unroll
        for (int mt = 0; mt < 4; ++mt)
          acc[mt][nt] = __builtin_amdgcn_mfma_f32_16x16x32_bf16(xk[mt], bfr, acc[mt][nt], 0, 0, 0);
      }
    }
  };

  // ---- stage V (cols 256 + w*32): per-(nt,k2) half-pass through stripe ----
  {
    f4v acc[4][2];
#pragma unroll
    for (int mt = 0; mt < 4; ++mt) { acc[mt][0] = zf; acc[mt][1] = zf; }
    run_qkv(256 + w * 32, acc);
#pragma unroll
    for (int nt = 0; nt < 2; ++nt)
#pragma unroll
      for (int k2 = 0; k2 < 2; ++k2) {
#pragma unroll
        for (int mh = 0; mh < 2; ++mh) {
          int mt = k2 * 2 + mh;
          union { uint2 u; bf16 h[4]; } pk;
#pragma unroll
          for (int r = 0; r < 4; ++r) pk.h[r] = __float2bfloat16(acc[mt][nt][r]);
          // stripe row = l16 (dim), local token col byte = mh*32 + quad*8
          *(uint2*)(sb + l16 * 64 + ((mh * 32 + quad * 8) ^ sswz)) = pk.u;
        }
        vf[k2][nt] = *(const bf8v*)(sb + l16 * 64 + ((quad * 16) ^ sswz));
      }
  }

  // ---- stage Q (cols 0 + w*32): per-mt token-major stripe [16][32] ----
  {
    f4v acc[4][2];
#pragma unroll
    for (int mt = 0; mt < 4; ++mt) { acc[mt][0] = zf; acc[mt][1] = zf; }
    run_qkv(w * 32, acc);
#pragma unroll
    for (int mt = 0; mt < 4; ++mt) {
#pragma unroll
      for (int nt = 0; nt < 2; ++nt)
#pragma unroll
        for (int r = 0; r < 4; ++r)
          *(bf16*)(sb + (quad * 4 + r) * 64 +
                   ((nt * 32 + l16 * 2) ^ ((((quad * 2) + (r >> 1)) & 3) << 4))) =
              __float2bfloat16(acc[mt][nt][r]);
      qf[mt] = *(const bf8v*)(sb + l16 * 64 + ((quad * 16) ^ sswz));
    }
  }

  // ---- stage K (cols 128 + w*32): per-mt stripe, kf[mt] = K tokens mt*16.. ----
  {
    f4v acc[4][2];
#pragma unroll
    for (int mt = 0; mt < 4; ++mt) { acc[mt][0] = zf; acc[mt][1] = zf; }
    run_qkv(128 + w * 32, acc);
#pragma unroll
    for (int mt = 0; mt < 4; ++mt) {
#pragma unroll
      for (int nt = 0; nt < 2; ++nt)
#pragma unroll
        for (int r = 0; r < 4; ++r)
          *(bf16*)(sb + (quad * 4 + r) * 64 +
                   ((nt * 32 + l16 * 2) ^ ((((quad * 2) + (r >> 1)) & 3) << 4))) =
              __float2bfloat16(acc[mt][nt][r]);
      kf[mt] = *(const bf8v*)(sb + l16 * 64 + ((quad * 16) ^ sswz));
    }
  }

  __syncthreads();   // all waves done reading xls; os (same region) now writable

  // ---- attention: scores -> +bias -> softmax (quad shuffles) -> P@v ----
  const float scale = 0.1767766952966369f;   // 32^-0.5
  const bf16* bh = biasg + w * 4096;
  for (int mt = 0; mt < 4; ++mt) {
    f4v sc[4];
#pragma unroll
    for (int n4 = 0; n4 < 4; ++n4)
      sc[n4] = __builtin_amdgcn_mfma_f32_16x16x32_bf16(qf[mt], kf[n4], zf, 0, 0, 0);
    float p[4][4];
#pragma unroll
    for (int n4 = 0; n4 < 4; ++n4) {
      union { uint2 u; bf16 hh[4]; } bb;
      bb.u = *(const uint2*)(bh + mt * 1024 + n4 * 256 + quad * 64 + l16 * 4);
#pragma unroll
      for (int r = 0; r < 4; ++r)
        p[n4][r] = sc[n4][r] * scale + __bfloat162float(bb.hh[r]);
    }
#pragma unroll
    for (int r = 0; r < 4; ++r) {
      float m = fmaxf(fmaxf(p[0][r], p[1][r]), fmaxf(p[2][r], p[3][r]));
      m = fmaxf(m, __shfl_xor(m, 1, 16));
      m = fmaxf(m, __shfl_xor(m, 2, 16));
      m = fmaxf(m, __shfl_xor(m, 4, 16));
      m = fmaxf(m, __shfl_xor(m, 8, 16));
      float s = 0.f;
#pragma unroll
      for (int n4 = 0; n4 < 4; ++n4) { p[n4][r] = __expf(p[n4][r] - m); s += p[n4][r]; }
      s += __shfl_xor(s, 1, 16);
      s += __shfl_xor(s, 2, 16);
      s += __shfl_xor(s, 4, 16);
      s += __shfl_xor(s, 8, 16);
      float inv = __builtin_amdgcn_rcpf(s);
#pragma unroll
      for (int n4 = 0; n4 < 4; ++n4) p[n4][r] *= inv;
    }
    // P transpose: two half-passes (by k2) through [16][32] stripe, PV fused
    f4v o2[2] = {zf, zf};
#pragma unroll
    for (int k2 = 0; k2 < 2; ++k2) {
#pragma unroll
      for (int nh = 0; nh < 2; ++nh) {
        int n4 = k2 * 2 + nh;
#pragma unroll
        for (int r = 0; r < 4; ++r)
          *(bf16*)(sb + (quad * 4 + r) * 64 +
                   ((nh * 32 + l16 * 2) ^ ((((quad * 2) + (r >> 1)) & 3) << 4))) =
              __float2bfloat16(p[n4][r]);
      }
      bf8v pf = *(const bf8v*)(sb + l16 * 64 + ((quad * 16) ^ sswz));
#pragma unroll
      for (int nt = 0; nt < 2; ++nt)
        o2[nt] = __builtin_amdgcn_mfma_f32_16x16x32_bf16(pf, vf[k2][nt], o2[nt], 0, 0, 0);
    }
#pragma unroll
    for (int nt = 0; nt < 2; ++nt) {
      union { uint2 u; bf16 h[4]; } pk;
#pragma unroll
      for (int r = 0; r < 4; ++r) pk.h[r] = __float2bfloat16(o2[nt][r]);
      // os row = mt*16+quad*4+r, col = w*32+nt*16+l16 (scalar, swizzled)
#pragma unroll
      for (int r = 0; r < 4; ++r) {
        int row = mt * 16 + quad * 4 + r;
        *(bf16*)(smc + row * 256 +
                 (((w * 32 + nt * 16 + l16) * 2) ^ ((row & 7) << 4))) = pk.h[r];
      }
    }
  }

  __syncthreads();   // os fully written

  // ---- proj: out = os @ W_proj + b_proj ; wave w covers cols [w*32, w*32+32) ----
  f4v pa[4][2];
#pragma unroll
  for (int mt = 0; mt < 4; ++mt) { pa[mt][0] = zf; pa[mt][1] = zf; }
#pragma unroll
  for (int ks = 0; ks < 4; ++ks) {
    bf8v oa[4];
#pragma unroll
    for (int mt = 0; mt < 4; ++mt)
      oa[mt] = *(const bf8v*)(smc + (mt * 16 + l16) * 256 + ((ks * 64 + quad * 16) ^ rsw));
#pragma unroll
    for (int nt = 0; nt < 2; ++nt) {
      bf8v bfr = *(const bf8v*)(WprojT + (size_t)(w * 32 + nt * 16 + l16) * 128 + ks * 32 + quad * 8);
#pragma unroll
      for (int mt = 0; mt < 4; ++mt)
        pa[mt][nt] = __builtin_amdgcn_mfma_f32_16x16x32_bf16(oa[mt], bfr, pa[mt][nt], 0, 0, 0);
    }
  }

  // ---- epilogue: staged coalesced full-line stores (no partial-line RMW) ----
  if (!isbf) {
    // Two 32-row chunks through dead xls region: [32][128] f32 swizzled = 16 KB.
    float* ob = (float*)outp + (size_t)b * 8192;
    float bbv[2];
#pragma unroll
    for (int nt = 0; nt < 2; ++nt)
      bbv[nt] = ((const float*)bprojp)[w * 32 + nt * 16 + l16];
#pragma unroll
    for (int half = 0; half < 2; ++half) {
      __syncthreads();   // proj reads of os (or prev chunk copy) complete
#pragma unroll
      for (int nt = 0; nt < 2; ++nt) {
        int c = w * 32 + nt * 16 + l16;
#pragma unroll
        for (int m2 = 0; m2 < 2; ++m2) {
          int mt = half * 2 + m2;
#pragma unroll
          for (int r = 0; r < 4; ++r) {
            int row = m2 * 16 + quad * 4 + r;
            *(float*)(smc + row * 512 + ((c * 4) ^ ((row & 7) << 4))) =
                pa[mt][nt][r] + bbv[nt];
          }
        }
      }
      __syncthreads();
#pragma unroll
      for (int it = 0; it < 4; ++it) {
        int e4 = (tid + it * 256) * 4;           // 0..4095 floats
        int row = e4 >> 7, colb = (e4 & 127) * 4;
        *(f4v*)(ob + half * 4096 + e4) =
            *(const f4v*)(smc + row * 512 + (colb ^ ((row & 7) << 4)));
      }
    }
  } else {
    // bf16 out: stage via xls region (dead after proj reads), coalesced copy
    __syncthreads();
#pragma unroll
    for (int nt = 0; nt < 2; ++nt) {
      int c = w * 32 + nt * 16 + l16;
      float bb = __bfloat162float(((const bf16*)bprojp)[c]);
#pragma unroll
      for (int mt = 0; mt < 4; ++mt)
#pragma unroll
        for (int r = 0; r < 4; ++r) {
          int row = mt * 16 + quad * 4 + r;
          *(bf16*)(smc + row * 256 + ((c * 2) ^ ((row & 7) << 4))) =
              __float2bfloat16(pa[mt][nt][r] + bb);
        }
    }
    __syncthreads();
    bf16* ob = (bf16*)outp + (size_t)b * 8192;
#pragma unroll
    for (int it = 0; it < 4; ++it) {
      int e = (tid + it * 256) * 8;
      int row = e >> 7, colb = (e & 127) * 2;
      *(uint4*)(ob + e) = *(const uint4*)(smc + row * 256 + (colb ^ ((row & 7) << 4)));
    }
  }
}

extern "C" void kernel_launch(void* const* d_in, const int* in_sizes, int n_in,
                              void* d_out, int out_size, void* d_ws, size_t ws_size,
                              hipStream_t stream) {
  const void* x      = d_in[0];
  const void* Wqkv   = d_in[1];
  const void* Wproj  = d_in[2];
  const void* bproj  = d_in[3];
  const void* w1     = d_in[4];
  const void* b1     = d_in[5];
  const void* w2     = d_in[6];
  const void* hts    = d_in[7];
  const void* pps    = d_in[8];
  const void* ws1    = d_in[9];
  const void* ws2    = d_in[10];
  const int*  rel    = (const int*)d_in[11];
  const void* coords = d_in[12];
  char* ws  = (char*)d_ws;

  prep_transpose<<<256, 256, 0, stream>>>(Wqkv, Wproj, coords, ws);
  prep_table<<<225, 512, 0, stream>>>(coords, w1, b1, w2, hts, pps, ws1, ws2, ws);
  prep_gather<<<16, 256, 0, stream>>>(rel, ws);
  wattn_main<<<4096, 256, 0, stream>>>(x, ws, bproj, coords, d_out);
}

// Round 4
// 336.095 us; speedup vs baseline: 1.6161x; 1.6161x over previous
//
#include <hip/hip_runtime.h>
#include <hip/hip_bf16.h>

typedef __hip_bfloat16 bf16;
typedef __bf16 bf8v __attribute__((ext_vector_type(8)));
typedef float f4v __attribute__((ext_vector_type(4)));

// workspace layout (bytes)
#define WS_BIAS   0        // bf16, MFMA-C-layout-permuted [4][4][4][4][16][4] = 32768
#define WS_TABLE  32768    // float[225][4]    = 3600 (padded to 4096)
#define WS_QKVT   36864    // bf16[384][128]   = 98304
#define WS_PROJT  135168   // bf16[128][128]   = 32768

__device__ __forceinline__ float rdf(const void* p, int i, int isbf) {
  return isbf ? __bfloat162float(((const bf16*)p)[i]) : ((const float*)p)[i];
}

// dtype detect: coords[0] == -1.0 exactly. fp32 -1.0 -> low 16 bits 0x0000;
// bf16 -1.0 -> 0xBF80. Each kernel derives this itself (no separate kernel).
__device__ __forceinline__ int dtflag(const void* coords) {
  return (*(const unsigned short*)coords != 0) ? 1 : 0;
}

__global__ void prep_transpose(const void* __restrict__ Wqkv,
                               const void* __restrict__ Wproj,
                               const void* __restrict__ coords,
                               char* __restrict__ ws) {
  int idx = blockIdx.x * 256 + threadIdx.x;   // 65536 threads
  int isbf = dtflag(coords);
  bf16* qt = (bf16*)(ws + WS_QKVT);
  bf16* pt = (bf16*)(ws + WS_PROJT);
  if (idx < 384 * 128) {
    int c = idx >> 7, k = idx & 127;
    qt[idx] = __float2bfloat16(rdf(Wqkv, k * 384 + c, isbf));
  } else {
    int j = idx - 384 * 128;                  // < 16384
    int c = j >> 7, k = j & 127;
    pt[j] = __float2bfloat16(rdf(Wproj, k * 128 + c, isbf));
  }
}

// 225 blocks x 512 threads: one hidden unit per thread, reduce across block.
__global__ void prep_table(const void* __restrict__ coords,
                           const void* __restrict__ w1,
                           const void* __restrict__ b1,
                           const void* __restrict__ w2,
                           const void* __restrict__ hts,
                           const void* __restrict__ pps,
                           const void* __restrict__ ws1,
                           const void* __restrict__ ws2,
                           char* __restrict__ ws) {
  __shared__ float red[8][4];
  const int r = blockIdx.x;       // 0..224
  const int j = threadIdx.x;      // 0..511
  const int isbf = dtflag(coords);
  float* table = (float*)(ws + WS_TABLE);

  float ht  = log1pf(__expf(rdf(hts, 0, isbf)));                 // softplus
  float pp  = 1.f / (1.f + __expf(-rdf(pps, 0, isbf)));          // sigmoid
  float wsv = log1pf(__expf(rdf(ws1, 0, isbf))) /
              log1pf(__expf(rdf(ws2, 0, isbf)));
  float t0 = rdf(coords, 2 * r + 0, isbf) * ht;
  float t1 = rdf(coords, 2 * r + 1, isbf) * ht;
  float s0 = (t0 > 0.f) ? 1.f : ((t0 < 0.f) ? -1.f : 0.f);
  float s1 = (t1 > 0.f) ? 1.f : ((t1 < 0.f) ? -1.f : 0.f);
  float u0 = s0 * __powf(fabsf(t0) + 1e-6f, pp) * wsv;
  float u1 = s1 * __powf(fabsf(t1) + 1e-6f, pp) * wsv;

  float h = u0 * rdf(w1, j, isbf) + u1 * rdf(w1, 512 + j, isbf) + rdf(b1, j, isbf);
  h = fmaxf(h, 0.f);
  float a[4];
#pragma unroll
  for (int q = 0; q < 4; ++q) a[q] = h * rdf(w2, 4 * j + q, isbf);
#pragma unroll
  for (int off = 1; off < 64; off <<= 1)
#pragma unroll
    for (int q = 0; q < 4; ++q) a[q] += __shfl_xor(a[q], off);
  int wv = j >> 6, ln = j & 63;
  if (ln == 0) {
#pragma unroll
    for (int q = 0; q < 4; ++q) red[wv][q] = a[q];
  }
  __syncthreads();
  if (j < 4) {
    float s = 0.f;
#pragma unroll
    for (int w8 = 0; w8 < 8; ++w8) s += red[w8][j];
    table[r * 4 + j] = s;
  }
}

// Permute bias into exact MFMA C-layout order:
//   elem = h*4096 + mt*1024 + n4*256 + quad*64 + l16*4 + r
// so wattn_main reads one uint2 (4 bf16, r=0..3) per (mt, n4).
__global__ void prep_gather(const int* __restrict__ rel, char* __restrict__ ws) {
  int pos = blockIdx.x * 256 + threadIdx.x;   // 4096
  const float* table = (const float*)(ws + WS_TABLE);
  bf16* bias = (bf16*)(ws + WS_BIAS);
  int h = pos >> 10, rest = pos & 1023;
  int mt = rest >> 8, n4 = (rest >> 6) & 3, quad = (rest >> 4) & 3, l16 = rest & 15;
  int jj = n4 * 16 + l16;
  union { uint2 u; bf16 hh[4]; } pk;
#pragma unroll
  for (int r = 0; r < 4; ++r) {
    int i = mt * 16 + quad * 4 + r;
    int rr = rel[i * 64 + jj];
    pk.hh[r] = __float2bfloat16(table[rr * 4 + h]);
  }
  *(uint2*)(bias + pos * 4) = pk.u;
}

// One block per window; wave w == head h. LDS = 20,480 B -> 8 blocks/CU paper.
//   [0, 16384)      xls : x tile bf16 [64][128], XOR-swizzled byte^=(row&7)<<4
//                   -> reused as os [64][128] (same swizzle)
//                   -> reused as fp32 epilogue staging [32][128], byte^=(row&7)<<4
//   [16384, 20480)  per-wave stripe [16][32] bf16 (64 B rows), 1024 B each,
//                   XOR-swizzled byte^=((row>>1)&3)<<4.  V and P transposes run
//                   as two half-passes (by k2); Q/K single-pass as before.
// __launch_bounds__(256,4): VGPR cap 128. Natural alloc ~56 <= 64 means the HW
// can still co-schedule 8 blocks/CU; capping tighter ((256,6)->40VGPR,
// (256,8)->32VGPR) caused spill storms (+0.3..1.0 GB HBM/dispatch). DO NOT cap.
__global__ __launch_bounds__(256, 4) void wattn_main(
    const void* __restrict__ xp,
    const char* __restrict__ ws,
    const void* __restrict__ bprojp,
    const void* __restrict__ coords,
    void* __restrict__ outp) {
  __shared__ alignas(16) char smem[20480];
  char* smc = smem;
  const int tid  = threadIdx.x;
  const int w    = tid >> 6;
  const int lane = tid & 63;
  const int l16  = lane & 15;
  const int quad = lane >> 4;
  char* sb = smc + 16384 + w * 1024;          // per-wave stripe base
  const int sswz = ((l16 >> 1) & 3) << 4;     // stripe read-swizzle (row = l16)
  const int rsw  = (l16 & 7) << 4;            // xls read-swizzle (row = mt*16+l16)

  const int isbf = dtflag(coords);
  const bf16* WqkvT  = (const bf16*)(ws + WS_QKVT);
  const bf16* WprojT = (const bf16*)(ws + WS_PROJT);
  const bf16* biasg  = (const bf16*)(ws + WS_BIAS);

  const int b = blockIdx.x;

  // ---- stage x -> LDS (bf16 [64][128] swizzled) ----
  if (isbf) {
    const bf16* xb = (const bf16*)xp + (size_t)b * 8192;
#pragma unroll
    for (int it = 0; it < 4; ++it) {
      int e = (tid + it * 256) * 8;
      int row = e >> 7, colb = (e & 127) * 2;
      *(uint4*)(smc + row * 256 + (colb ^ ((row & 7) << 4))) = *(const uint4*)(xb + e);
    }
  } else {
    const float* xb = (const float*)xp + (size_t)b * 8192;
#pragma unroll
    for (int it = 0; it < 4; ++it) {
      int e = (tid + it * 256) * 8;
      int row = e >> 7, colb = (e & 127) * 2;
      f4v a = *(const f4v*)(xb + e);
      f4v c = *(const f4v*)(xb + e + 4);
      union { uint4 u; bf16 h[8]; } pk;
#pragma unroll
      for (int jj = 0; jj < 4; ++jj) {
        pk.h[jj]     = __float2bfloat16(a[jj]);
        pk.h[4 + jj] = __float2bfloat16(c[jj]);
      }
      *(uint4*)(smc + row * 256 + (colb ^ ((row & 7) << 4))) = pk.u;
    }
  }
  __syncthreads();

  const f4v zf = {0.f, 0.f, 0.f, 0.f};
  bf8v vf[2][2], qf[4], kf[4];

  auto run_qkv = [&](int colbase, f4v (&acc)[4][2]) {
    const bf16* Bb = WqkvT + (size_t)colbase * 128;
#pragma unroll
    for (int ks = 0; ks < 4; ++ks) {
      bf8v xk[4];
#pragma unroll
      for (int mt = 0; mt < 4; ++mt)
        xk[mt] = *(const bf8v*)(smc + (mt * 16 + l16) * 256 + ((ks * 64 + quad * 16) ^ rsw));
#pragma unroll
      for (int nt = 0; nt < 2; ++nt) {
        bf8v bfr = *(const bf8v*)(Bb + (nt * 16 + l16) * 128 + ks * 32 + quad * 8);
#pragma unroll
        for (int mt = 0; mt < 4; ++mt)
          acc[mt][nt] = __builtin_amdgcn_mfma_f32_16x16x32_bf16(xk[mt], bfr, acc[mt][nt], 0, 0, 0);
      }
    }
  };

  // ---- stage V (cols 256 + w*32): per-(nt,k2) half-pass through stripe ----
  {
    f4v acc[4][2];
#pragma unroll
    for (int mt = 0; mt < 4; ++mt) { acc[mt][0] = zf; acc[mt][1] = zf; }
    run_qkv(256 + w * 32, acc);
#pragma unroll
    for (int nt = 0; nt < 2; ++nt)
#pragma unroll
      for (int k2 = 0; k2 < 2; ++k2) {
#pragma unroll
        for (int mh = 0; mh < 2; ++mh) {
          int mt = k2 * 2 + mh;
          union { uint2 u; bf16 h[4]; } pk;
#pragma unroll
          for (int r = 0; r < 4; ++r) pk.h[r] = __float2bfloat16(acc[mt][nt][r]);
          // stripe row = l16 (dim), local token col byte = mh*32 + quad*8
          *(uint2*)(sb + l16 * 64 + ((mh * 32 + quad * 8) ^ sswz)) = pk.u;
        }
        vf[k2][nt] = *(const bf8v*)(sb + l16 * 64 + ((quad * 16) ^ sswz));
      }
  }

  // ---- stage Q (cols 0 + w*32): per-mt token-major stripe [16][32] ----
  {
    f4v acc[4][2];
#pragma unroll
    for (int mt = 0; mt < 4; ++mt) { acc[mt][0] = zf; acc[mt][1] = zf; }
    run_qkv(w * 32, acc);
#pragma unroll
    for (int mt = 0; mt < 4; ++mt) {
#pragma unroll
      for (int nt = 0; nt < 2; ++nt)
#pragma unroll
        for (int r = 0; r < 4; ++r)
          *(bf16*)(sb + (quad * 4 + r) * 64 +
                   ((nt * 32 + l16 * 2) ^ ((((quad * 2) + (r >> 1)) & 3) << 4))) =
              __float2bfloat16(acc[mt][nt][r]);
      qf[mt] = *(const bf8v*)(sb + l16 * 64 + ((quad * 16) ^ sswz));
    }
  }

  // ---- stage K (cols 128 + w*32): per-mt stripe, kf[mt] = K tokens mt*16.. ----
  {
    f4v acc[4][2];
#pragma unroll
    for (int mt = 0; mt < 4; ++mt) { acc[mt][0] = zf; acc[mt][1] = zf; }
    run_qkv(128 + w * 32, acc);
#pragma unroll
    for (int mt = 0; mt < 4; ++mt) {
#pragma unroll
      for (int nt = 0; nt < 2; ++nt)
#pragma unroll
        for (int r = 0; r < 4; ++r)
          *(bf16*)(sb + (quad * 4 + r) * 64 +
                   ((nt * 32 + l16 * 2) ^ ((((quad * 2) + (r >> 1)) & 3) << 4))) =
              __float2bfloat16(acc[mt][nt][r]);
      kf[mt] = *(const bf8v*)(sb + l16 * 64 + ((quad * 16) ^ sswz));
    }
  }

  __syncthreads();   // all waves done reading xls; os (same region) now writable

  // ---- attention: scores -> +bias -> softmax (quad shuffles) -> P@v ----
  const float scale = 0.1767766952966369f;   // 32^-0.5
  const bf16* bh = biasg + w * 4096;
  for (int mt = 0; mt < 4; ++mt) {
    f4v sc[4];
#pragma unroll
    for (int n4 = 0; n4 < 4; ++n4)
      sc[n4] = __builtin_amdgcn_mfma_f32_16x16x32_bf16(qf[mt], kf[n4], zf, 0, 0, 0);
    float p[4][4];
#pragma unroll
    for (int n4 = 0; n4 < 4; ++n4) {
      union { uint2 u; bf16 hh[4]; } bb;
      bb.u = *(const uint2*)(bh + mt * 1024 + n4 * 256 + quad * 64 + l16 * 4);
#pragma unroll
      for (int r = 0; r < 4; ++r)
        p[n4][r] = sc[n4][r] * scale + __bfloat162float(bb.hh[r]);
    }
#pragma unroll
    for (int r = 0; r < 4; ++r) {
      float m = fmaxf(fmaxf(p[0][r], p[1][r]), fmaxf(p[2][r], p[3][r]));
      m = fmaxf(m, __shfl_xor(m, 1, 16));
      m = fmaxf(m, __shfl_xor(m, 2, 16));
      m = fmaxf(m, __shfl_xor(m, 4, 16));
      m = fmaxf(m, __shfl_xor(m, 8, 16));
      float s = 0.f;
#pragma unroll
      for (int n4 = 0; n4 < 4; ++n4) { p[n4][r] = __expf(p[n4][r] - m); s += p[n4][r]; }
      s += __shfl_xor(s, 1, 16);
      s += __shfl_xor(s, 2, 16);
      s += __shfl_xor(s, 4, 16);
      s += __shfl_xor(s, 8, 16);
      float inv = __builtin_amdgcn_rcpf(s);
#pragma unroll
      for (int n4 = 0; n4 < 4; ++n4) p[n4][r] *= inv;
    }
    // P transpose: two half-passes (by k2) through [16][32] stripe, PV fused
    f4v o2[2] = {zf, zf};
#pragma unroll
    for (int k2 = 0; k2 < 2; ++k2) {
#pragma unroll
      for (int nh = 0; nh < 2; ++nh) {
        int n4 = k2 * 2 + nh;
#pragma unroll
        for (int r = 0; r < 4; ++r)
          *(bf16*)(sb + (quad * 4 + r) * 64 +
                   ((nh * 32 + l16 * 2) ^ ((((quad * 2) + (r >> 1)) & 3) << 4))) =
              __float2bfloat16(p[n4][r]);
      }
      bf8v pf = *(const bf8v*)(sb + l16 * 64 + ((quad * 16) ^ sswz));
#pragma unroll
      for (int nt = 0; nt < 2; ++nt)
        o2[nt] = __builtin_amdgcn_mfma_f32_16x16x32_bf16(pf, vf[k2][nt], o2[nt], 0, 0, 0);
    }
#pragma unroll
    for (int nt = 0; nt < 2; ++nt) {
      union { uint2 u; bf16 h[4]; } pk;
#pragma unroll
      for (int r = 0; r < 4; ++r) pk.h[r] = __float2bfloat16(o2[nt][r]);
      // os row = mt*16+quad*4+r, col = w*32+nt*16+l16 (scalar, swizzled)
#pragma unroll
      for (int r = 0; r < 4; ++r) {
        int row = mt * 16 + quad * 4 + r;
        *(bf16*)(smc + row * 256 +
                 (((w * 32 + nt * 16 + l16) * 2) ^ ((row & 7) << 4))) = pk.h[r];
      }
    }
  }

  __syncthreads();   // os fully written

  // ---- proj: out = os @ W_proj + b_proj ; wave w covers cols [w*32, w*32+32) ----
  f4v pa[4][2];
#pragma unroll
  for (int mt = 0; mt < 4; ++mt) { pa[mt][0] = zf; pa[mt][1] = zf; }
#pragma unroll
  for (int ks = 0; ks < 4; ++ks) {
    bf8v oa[4];
#pragma unroll
    for (int mt = 0; mt < 4; ++mt)
      oa[mt] = *(const bf8v*)(smc + (mt * 16 + l16) * 256 + ((ks * 64 + quad * 16) ^ rsw));
#pragma unroll
    for (int nt = 0; nt < 2; ++nt) {
      bf8v bfr = *(const bf8v*)(WprojT + (size_t)(w * 32 + nt * 16 + l16) * 128 + ks * 32 + quad * 8);
#pragma unroll
      for (int mt = 0; mt < 4; ++mt)
        pa[mt][nt] = __builtin_amdgcn_mfma_f32_16x16x32_bf16(oa[mt], bfr, pa[mt][nt], 0, 0, 0);
    }
  }

  // ---- epilogue: staged coalesced full-line stores (no partial-line RMW) ----
  if (!isbf) {
    // Two 32-row chunks through dead xls region: [32][128] f32 swizzled = 16 KB.
    float* ob = (float*)outp + (size_t)b * 8192;
    float bbv[2];
#pragma unroll
    for (int nt = 0; nt < 2; ++nt)
      bbv[nt] = ((const float*)bprojp)[w * 32 + nt * 16 + l16];
#pragma unroll
    for (int half = 0; half < 2; ++half) {
      __syncthreads();   // proj reads of os (or prev chunk copy) complete
#pragma unroll
      for (int nt = 0; nt < 2; ++nt) {
        int c = w * 32 + nt * 16 + l16;
#pragma unroll
        for (int m2 = 0; m2 < 2; ++m2) {
          int mt = half * 2 + m2;
#pragma unroll
          for (int r = 0; r < 4; ++r) {
            int row = m2 * 16 + quad * 4 + r;
            *(float*)(smc + row * 512 + ((c * 4) ^ ((row & 7) << 4))) =
                pa[mt][nt][r] + bbv[nt];
          }
        }
      }
      __syncthreads();
#pragma unroll
      for (int it = 0; it < 4; ++it) {
        int e4 = (tid + it * 256) * 4;           // 0..4095 floats
        int row = e4 >> 7, colb = (e4 & 127) * 4;
        *(f4v*)(ob + half * 4096 + e4) =
            *(const f4v*)(smc + row * 512 + (colb ^ ((row & 7) << 4)));
      }
    }
  } else {
    // bf16 out: stage via xls region (dead after proj reads), coalesced copy
    __syncthreads();
#pragma unroll
    for (int nt = 0; nt < 2; ++nt) {
      int c = w * 32 + nt * 16 + l16;
      float bb = __bfloat162float(((const bf16*)bprojp)[c]);
#pragma unroll
      for (int mt = 0; mt < 4; ++mt)
#pragma unroll
        for (int r = 0; r < 4; ++r) {
          int row = mt * 16 + quad * 4 + r;
          *(bf16*)(smc + row * 256 + ((c * 2) ^ ((row & 7) << 4))) =
              __float2bfloat16(pa[mt][nt][r] + bb);
        }
    }
    __syncthreads();
    bf16* ob = (bf16*)outp + (size_t)b * 8192;
#pragma unroll
    for (int it = 0; it < 4; ++it) {
      int e = (tid + it * 256) * 8;
      int row = e >> 7, colb = (e & 127) * 2;
      *(uint4*)(ob + e) = *(const uint4*)(smc + row * 256 + (colb ^ ((row & 7) << 4)));
    }
  }
}

extern "C" void kernel_launch(void* const* d_in, const int* in_sizes, int n_in,
                              void* d_out, int out_size, void* d_ws, size_t ws_size,
                              hipStream_t stream) {
  const void* x      = d_in[0];
  const void* Wqkv   = d_in[1];
  const void* Wproj  = d_in[2];
  const void* bproj  = d_in[3];
  const void* w1     = d_in[4];
  const void* b1     = d_in[5];
  const void* w2     = d_in[6];
  const void* hts    = d_in[7];
  const void* pps    = d_in[8];
  const void* ws1    = d_in[9];
  const void* ws2    = d_in[10];
  const int*  rel    = (const int*)d_in[11];
  const void* coords = d_in[12];
  char* ws  = (char*)d_ws;

  prep_transpose<<<256, 256, 0, stream>>>(Wqkv, Wproj, coords, ws);
  prep_table<<<225, 512, 0, stream>>>(coords, w1, b1, w2, hts, pps, ws1, ws2, ws);
  prep_gather<<<16, 256, 0, stream>>>(rel, ws);
  wattn_main<<<4096, 256, 0, stream>>>(x, ws, bproj, coords, d_out);
}

// Round 5
// 304.924 us; speedup vs baseline: 1.7813x; 1.1022x over previous
//
#include <hip/hip_runtime.h>
#include <hip/hip_bf16.h>

typedef __hip_bfloat16 bf16;
typedef __bf16 bf8v __attribute__((ext_vector_type(8)));
typedef float f4v __attribute__((ext_vector_type(4)));

// workspace layout (bytes)
#define WS_BIAS   0        // bf16, MFMA-C-layout-permuted (S^T orientation) = 32768
#define WS_TABLE  32768    // float[225][4]    = 3600 (padded to 4096)
#define WS_QKVT   36864    // bf16[384][128]   = 98304
#define WS_PROJT  135168   // bf16[128][128]   = 32768

__device__ __forceinline__ float rdf(const void* p, int i, int isbf) {
  return isbf ? __bfloat162float(((const bf16*)p)[i]) : ((const float*)p)[i];
}

// dtype detect: coords[0] == -1.0 exactly. fp32 -1.0 -> low 16 bits 0x0000;
// bf16 -1.0 -> 0xBF80. Each kernel derives this itself (no separate kernel).
__device__ __forceinline__ int dtflag(const void* coords) {
  return (*(const unsigned short*)coords != 0) ? 1 : 0;
}

__device__ __forceinline__ unsigned pkbf(float a, float b) {
  union { bf16 h[2]; unsigned u; } t;
  t.h[0] = __float2bfloat16(a);
  t.h[1] = __float2bfloat16(b);
  return t.u;
}

__global__ void prep_transpose(const void* __restrict__ Wqkv,
                               const void* __restrict__ Wproj,
                               const void* __restrict__ coords,
                               char* __restrict__ ws) {
  int idx = blockIdx.x * 256 + threadIdx.x;   // 65536 threads
  int isbf = dtflag(coords);
  bf16* qt = (bf16*)(ws + WS_QKVT);
  bf16* pt = (bf16*)(ws + WS_PROJT);
  if (idx < 384 * 128) {
    int c = idx >> 7, k = idx & 127;
    qt[idx] = __float2bfloat16(rdf(Wqkv, k * 384 + c, isbf));
  } else {
    int j = idx - 384 * 128;                  // < 16384
    int c = j >> 7, k = j & 127;
    pt[j] = __float2bfloat16(rdf(Wproj, k * 128 + c, isbf));
  }
}

// 225 blocks x 512 threads: one hidden unit per thread, reduce across block.
__global__ void prep_table(const void* __restrict__ coords,
                           const void* __restrict__ w1,
                           const void* __restrict__ b1,
                           const void* __restrict__ w2,
                           const void* __restrict__ hts,
                           const void* __restrict__ pps,
                           const void* __restrict__ ws1,
                           const void* __restrict__ ws2,
                           char* __restrict__ ws) {
  __shared__ float red[8][4];
  const int r = blockIdx.x;       // 0..224
  const int j = threadIdx.x;      // 0..511
  const int isbf = dtflag(coords);
  float* table = (float*)(ws + WS_TABLE);

  float ht  = log1pf(__expf(rdf(hts, 0, isbf)));                 // softplus
  float pp  = 1.f / (1.f + __expf(-rdf(pps, 0, isbf)));          // sigmoid
  float wsv = log1pf(__expf(rdf(ws1, 0, isbf))) /
              log1pf(__expf(rdf(ws2, 0, isbf)));
  float t0 = rdf(coords, 2 * r + 0, isbf) * ht;
  float t1 = rdf(coords, 2 * r + 1, isbf) * ht;
  float s0 = (t0 > 0.f) ? 1.f : ((t0 < 0.f) ? -1.f : 0.f);
  float s1 = (t1 > 0.f) ? 1.f : ((t1 < 0.f) ? -1.f : 0.f);
  float u0 = s0 * __powf(fabsf(t0) + 1e-6f, pp) * wsv;
  float u1 = s1 * __powf(fabsf(t1) + 1e-6f, pp) * wsv;

  float h = u0 * rdf(w1, j, isbf) + u1 * rdf(w1, 512 + j, isbf) + rdf(b1, j, isbf);
  h = fmaxf(h, 0.f);
  float a[4];
#pragma unroll
  for (int q = 0; q < 4; ++q) a[q] = h * rdf(w2, 4 * j + q, isbf);
#pragma unroll
  for (int off = 1; off < 64; off <<= 1)
#pragma unroll
    for (int q = 0; q < 4; ++q) a[q] += __shfl_xor(a[q], off);
  int wv = j >> 6, ln = j & 63;
  if (ln == 0) {
#pragma unroll
    for (int q = 0; q < 4; ++q) red[wv][q] = a[q];
  }
  __syncthreads();
  if (j < 4) {
    float s = 0.f;
#pragma unroll
    for (int w8 = 0; w8 < 8; ++w8) s += red[w8][j];
    table[r * 4 + j] = s;
  }
}

// Permute bias into S^T MFMA C-layout order (scores computed as K.Q^T):
//   elem = h*4096 + mt*1024 + n4*256 + quad*64 + l16*4 + r
//   value = bias[h][tok_q = mt*16 + l16][tok_k = n4*16 + quad*4 + r]
// wattn_main reads one uint2 (4 bf16, r=0..3) per (mt, n4) -- unchanged address.
__global__ void prep_gather(const int* __restrict__ rel, char* __restrict__ ws) {
  int pos = blockIdx.x * 256 + threadIdx.x;   // 4096
  const float* table = (const float*)(ws + WS_TABLE);
  bf16* bias = (bf16*)(ws + WS_BIAS);
  int h = pos >> 10, rest = pos & 1023;
  int mt = rest >> 8, n4 = (rest >> 6) & 3, quad = (rest >> 4) & 3, l16 = rest & 15;
  union { uint2 u; bf16 hh[4]; } pk;
#pragma unroll
  for (int r = 0; r < 4; ++r) {
    int rr = rel[(mt * 16 + l16) * 64 + (n4 * 16 + quad * 4 + r)];
    pk.hh[r] = __float2bfloat16(table[rr * 4 + h]);
  }
  *(uint2*)(bias + pos * 4) = pk.u;
}

// One block per window; wave w == head h. LDS (26,624 B total -> 6 blocks/CU):
//   [0, 17408)      xls : x staged as bf16 [64][136]  -> later reused as os [64][136]
//                   -> later reused as fp32 epilogue staging [32][132] (two chunks)
//   [17408, 26624)  per-wave stripe scratch, 2304 B each (write->read->overwrite).
// __launch_bounds__(256,4): natural VGPR fits; tighter caps ((256,6)->40VGPR,
// (256,8)->32VGPR) caused spill storms (+0.3..1.0 GB HBM/dispatch). DO NOT cap.
// Attention computes S^T = mfma(K, Q) so softmax is in-register (2 shuffles/mt)
// and P^T reaches the PV MFMA via cross-quad ds_bpermute -- no LDS round trip.
__global__ __launch_bounds__(256, 4) void wattn_main(
    const void* __restrict__ xp,
    const char* __restrict__ ws,
    const void* __restrict__ bprojp,
    const void* __restrict__ coords,
    void* __restrict__ outp) {
  __shared__ alignas(16) char smem[26624];
  bf16* xls = (bf16*)smem;                                  // [64][136]
  bf16* os  = (bf16*)smem;                                  // [64][136] (after stages)
  const int tid  = threadIdx.x;
  const int w    = tid >> 6;
  const int lane = tid & 63;
  const int l16  = lane & 15;
  const int quad = lane >> 4;
  bf16* scr = (bf16*)(smem + 17408 + w * 2304);             // 1152 bf16 elems

  const int isbf = dtflag(coords);
  const bf16* WqkvT  = (const bf16*)(ws + WS_QKVT);
  const bf16* WprojT = (const bf16*)(ws + WS_PROJT);
  const bf16* biasg  = (const bf16*)(ws + WS_BIAS);

  const int b = blockIdx.x;

  // ---- stage x -> LDS (bf16, padded rows: stride 136 elems = 272 B) ----
  if (isbf) {
    const bf16* xb = (const bf16*)xp + (size_t)b * 8192;
#pragma unroll
    for (int it = 0; it < 4; ++it) {
      int e = (tid + it * 256) * 8;
      int row = e >> 7, col = e & 127;
      *(uint4*)(xls + row * 136 + col) = *(const uint4*)(xb + e);
    }
  } else {
    const float* xb = (const float*)xp + (size_t)b * 8192;
#pragma unroll
    for (int it = 0; it < 4; ++it) {
      int e = (tid + it * 256) * 8;
      int row = e >> 7, col = e & 127;
      f4v a = *(const f4v*)(xb + e);
      f4v c = *(const f4v*)(xb + e + 4);
      union { uint4 u; bf16 h[8]; } pk;
#pragma unroll
      for (int jj = 0; jj < 4; ++jj) {
        pk.h[jj]     = __float2bfloat16(a[jj]);
        pk.h[4 + jj] = __float2bfloat16(c[jj]);
      }
      *(uint4*)(xls + row * 136 + col) = pk.u;
    }
  }
  __syncthreads();

  const f4v zf = {0.f, 0.f, 0.f, 0.f};
  bf8v vf[2][2], qf[4], kf[4];

  auto run_qkv = [&](int colbase, f4v (&acc)[4][2]) {
    const bf16* Bb = WqkvT + (size_t)colbase * 128;
#pragma unroll
    for (int ks = 0; ks < 4; ++ks) {
      bf8v xk[4];
#pragma unroll
      for (int mt = 0; mt < 4; ++mt)
        xk[mt] = *(const bf8v*)(xls + (mt * 16 + l16) * 136 + ks * 32 + quad * 8);
#pragma unroll
      for (int nt = 0; nt < 2; ++nt) {
        bf8v bfr = *(const bf8v*)(Bb + (nt * 16 + l16) * 128 + ks * 32 + quad * 8);
#pragma unroll
        for (int mt = 0; mt < 4; ++mt)
          acc[mt][nt] = __builtin_amdgcn_mfma_f32_16x16x32_bf16(xk[mt], bfr, acc[mt][nt], 0, 0, 0);
      }
    }
  };

  // ---- stage V (cols 256 + w*32): per-nt 16-row stripe [16][72] in scratch ----
  // vf[k2][nt] = V^T[dim = nt*16+l16][tok = k2*32+quad*8+j]  (A-frag of V^T)
  {
    f4v acc[4][2];
#pragma unroll
    for (int mt = 0; mt < 4; ++mt) { acc[mt][0] = zf; acc[mt][1] = zf; }
    run_qkv(256 + w * 32, acc);
#pragma unroll
    for (int nt = 0; nt < 2; ++nt) {
#pragma unroll
      for (int mt = 0; mt < 4; ++mt) {
        union { uint2 u; bf16 h[4]; } pk;
#pragma unroll
        for (int r = 0; r < 4; ++r) pk.h[r] = __float2bfloat16(acc[mt][nt][r]);
        *(uint2*)(scr + l16 * 72 + mt * 16 + quad * 4) = pk.u;
      }
#pragma unroll
      for (int k2 = 0; k2 < 2; ++k2)
        vf[k2][nt] = *(const bf8v*)(scr + l16 * 72 + k2 * 32 + quad * 8);
    }
  }

  // ---- stage Q (cols 0 + w*32): per-mt token-major stripe [16][40] ----
  {
    f4v acc[4][2];
#pragma unroll
    for (int mt = 0; mt < 4; ++mt) { acc[mt][0] = zf; acc[mt][1] = zf; }
    run_qkv(w * 32, acc);
#pragma unroll
    for (int mt = 0; mt < 4; ++mt) {
#pragma unroll
      for (int nt = 0; nt < 2; ++nt)
#pragma unroll
        for (int r = 0; r < 4; ++r)
          scr[(quad * 4 + r) * 40 + nt * 16 + l16] = __float2bfloat16(acc[mt][nt][r]);
      qf[mt] = *(const bf8v*)(scr + l16 * 40 + quad * 8);
    }
  }

  // ---- stage K (cols 128 + w*32): per-mt stripe, kf[mt] = K tokens mt*16.. ----
  {
    f4v acc[4][2];
#pragma unroll
    for (int mt = 0; mt < 4; ++mt) { acc[mt][0] = zf; acc[mt][1] = zf; }
    run_qkv(128 + w * 32, acc);
#pragma unroll
    for (int mt = 0; mt < 4; ++mt) {
#pragma unroll
      for (int nt = 0; nt < 2; ++nt)
#pragma unroll
        for (int r = 0; r < 4; ++r)
          scr[(quad * 4 + r) * 40 + nt * 16 + l16] = __float2bfloat16(acc[mt][nt][r]);
      kf[mt] = *(const bf8v*)(scr + l16 * 40 + quad * 8);
    }
  }

  __syncthreads();   // all waves done reading xls; os (same region) now writable

  // ---- attention: S^T = K.Q^T -> +bias -> in-register softmax -> O^T = V^T.P^T
  const float scale = 0.1767766952966369f;   // 32^-0.5
  const bf16* bh = biasg + w * 4096;
  const bool hi2 = (quad >> 1) != 0;          // n4-select after bpermute
  const int a0 = ((quad & 1) * 32 + l16) * 4; // src lane*4 (toks +0..3 of own 8)
  for (int mt = 0; mt < 4; ++mt) {
    // bias loads issued ahead of the MFMA chain (L2 latency overlap)
    uint2 bbu[4];
#pragma unroll
    for (int n4 = 0; n4 < 4; ++n4)
      bbu[n4] = *(const uint2*)(bh + mt * 1024 + n4 * 256 + quad * 64 + l16 * 4);
    // S^T strip: rows = tok_k (n4*16 + quad*4 + r), cols = tok_q (mt*16 + l16)
    f4v sc[4];
#pragma unroll
    for (int n4 = 0; n4 < 4; ++n4)
      sc[n4] = __builtin_amdgcn_mfma_f32_16x16x32_bf16(kf[n4], qf[mt], zf, 0, 0, 0);
    float p[4][4];
#pragma unroll
    for (int n4 = 0; n4 < 4; ++n4) {
      union { uint2 u; bf16 hh[4]; } bb; bb.u = bbu[n4];
#pragma unroll
      for (int r = 0; r < 4; ++r)
        p[n4][r] = sc[n4][r] * scale + __bfloat162float(bb.hh[r]);
    }
    // softmax over tok_k: 16 in-register values + 2 cross-quad shuffles
    float m0 = fmaxf(fmaxf(p[0][0], p[0][1]), fmaxf(p[0][2], p[0][3]));
    float m1 = fmaxf(fmaxf(p[1][0], p[1][1]), fmaxf(p[1][2], p[1][3]));
    float m2 = fmaxf(fmaxf(p[2][0], p[2][1]), fmaxf(p[2][2], p[2][3]));
    float m3 = fmaxf(fmaxf(p[3][0], p[3][1]), fmaxf(p[3][2], p[3][3]));
    float mx = fmaxf(fmaxf(m0, m1), fmaxf(m2, m3));
    mx = fmaxf(mx, __shfl_xor(mx, 16));
    mx = fmaxf(mx, __shfl_xor(mx, 32));
    float s = 0.f;
#pragma unroll
    for (int n4 = 0; n4 < 4; ++n4) {
      float t0 = __expf(p[n4][0] - mx), t1 = __expf(p[n4][1] - mx);
      float t2 = __expf(p[n4][2] - mx), t3 = __expf(p[n4][3] - mx);
      p[n4][0] = t0; p[n4][1] = t1; p[n4][2] = t2; p[n4][3] = t3;
      s += (t0 + t1) + (t2 + t3);
    }
    s += __shfl_xor(s, 16);
    s += __shfl_xor(s, 32);
    float inv = __builtin_amdgcn_rcpf(s);
    unsigned pk32[4][2];
#pragma unroll
    for (int n4 = 0; n4 < 4; ++n4) {
      pk32[n4][0] = pkbf(p[n4][0] * inv, p[n4][1] * inv);
      pk32[n4][1] = pkbf(p[n4][2] * inv, p[n4][3] * inv);
    }
    // P^T B-frag via cross-quad bpermute: lane (quad,l16) elem j needs
    // tok_k = ks*32 + quad*8 + j of tok_q = mt*16 + l16 (same l16, other quads)
    f4v o2[2] = {zf, zf};
#pragma unroll
    for (int ks = 0; ks < 2; ++ks) {
      unsigned w0a = __builtin_amdgcn_ds_bpermute(a0,      (int)pk32[2 * ks][0]);
      unsigned w0b = __builtin_amdgcn_ds_bpermute(a0,      (int)pk32[2 * ks + 1][0]);
      unsigned w1a = __builtin_amdgcn_ds_bpermute(a0,      (int)pk32[2 * ks][1]);
      unsigned w1b = __builtin_amdgcn_ds_bpermute(a0,      (int)pk32[2 * ks + 1][1]);
      unsigned w2a = __builtin_amdgcn_ds_bpermute(a0 + 64, (int)pk32[2 * ks][0]);
      unsigned w2b = __builtin_amdgcn_ds_bpermute(a0 + 64, (int)pk32[2 * ks + 1][0]);
      unsigned w3a = __builtin_amdgcn_ds_bpermute(a0 + 64, (int)pk32[2 * ks][1]);
      unsigned w3b = __builtin_amdgcn_ds_bpermute(a0 + 64, (int)pk32[2 * ks + 1][1]);
      union { unsigned u[4]; bf8v v; } pf;
      pf.u[0] = hi2 ? w0b : w0a;
      pf.u[1] = hi2 ? w1b : w1a;
      pf.u[2] = hi2 ? w2b : w2a;
      pf.u[3] = hi2 ? w3b : w3a;
#pragma unroll
      for (int nt = 0; nt < 2; ++nt)
        o2[nt] = __builtin_amdgcn_mfma_f32_16x16x32_bf16(vf[ks][nt], pf.v, o2[nt], 0, 0, 0);
    }
    // O^T C-layout: col = tok_q = mt*16+l16 (os row), row = dim = nt*16+quad*4+r
    // -> dims contiguous in r: uint2 stores into token-major os
#pragma unroll
    for (int nt = 0; nt < 2; ++nt) {
      union { uint2 u; bf16 h[4]; } pk;
#pragma unroll
      for (int r = 0; r < 4; ++r) pk.h[r] = __float2bfloat16(o2[nt][r]);
      *(uint2*)(os + (mt * 16 + l16) * 136 + w * 32 + nt * 16 + quad * 4) = pk.u;
    }
  }

  __syncthreads();   // os fully written

  // ---- proj: out = os @ W_proj + b_proj ; wave w covers cols [w*32, w*32+32) ----
  f4v pa[4][2];
#pragma unroll
  for (int mt = 0; mt < 4; ++mt) { pa[mt][0] = zf; pa[mt][1] = zf; }
#pragma unroll
  for (int ks = 0; ks < 4; ++ks) {
    bf8v oa[4];
#pragma unroll
    for (int mt = 0; mt < 4; ++mt)
      oa[mt] = *(const bf8v*)(os + (mt * 16 + l16) * 136 + ks * 32 + quad * 8);
#pragma unroll
    for (int nt = 0; nt < 2; ++nt) {
      bf8v bfr = *(const bf8v*)(WprojT + (size_t)(w * 32 + nt * 16 + l16) * 128 + ks * 32 + quad * 8);
#pragma unroll
      for (int mt = 0; mt < 4; ++mt)
        pa[mt][nt] = __builtin_amdgcn_mfma_f32_16x16x32_bf16(oa[mt], bfr, pa[mt][nt], 0, 0, 0);
    }
  }

  // ---- epilogue: staged coalesced full-line stores (no partial-line RMW) ----
  if (!isbf) {
    // Two 32-row chunks through dead os region: [32][132] fp32 = 16.9 KB.
    float* ob  = (float*)outp + (size_t)b * 8192;
    float* fsf = (float*)smem;
    float bbv[2];
#pragma unroll
    for (int nt = 0; nt < 2; ++nt)
      bbv[nt] = ((const float*)bprojp)[w * 32 + nt * 16 + l16];
#pragma unroll
    for (int half = 0; half < 2; ++half) {
      __syncthreads();   // proj reads of os (or prev chunk copy) complete
#pragma unroll
      for (int nt = 0; nt < 2; ++nt) {
        int c = w * 32 + nt * 16 + l16;
#pragma unroll
        for (int m2 = 0; m2 < 2; ++m2) {
          int mt = half * 2 + m2;
#pragma unroll
          for (int r = 0; r < 4; ++r)
            fsf[(m2 * 16 + quad * 4 + r) * 132 + c] = pa[mt][nt][r] + bbv[nt];
        }
      }
      __syncthreads();
#pragma unroll
      for (int it = 0; it < 4; ++it) {
        int e4 = (tid + it * 256) * 4;           // 0..4095 floats
        int row = e4 >> 7, col = e4 & 127;
        *(f4v*)(ob + half * 4096 + e4) = *(const f4v*)(fsf + row * 132 + col);
      }
    }
  } else {
    // bf16 out: stage via xls region (dead after proj reads), coalesced copy
    __syncthreads();
#pragma unroll
    for (int nt = 0; nt < 2; ++nt) {
      int c = w * 32 + nt * 16 + l16;
      float bb = __bfloat162float(((const bf16*)bprojp)[c]);
#pragma unroll
      for (int mt = 0; mt < 4; ++mt)
#pragma unroll
        for (int r = 0; r < 4; ++r)
          xls[(mt * 16 + quad * 4 + r) * 136 + c] = __float2bfloat16(pa[mt][nt][r] + bb);
    }
    __syncthreads();
    bf16* ob = (bf16*)outp + (size_t)b * 8192;
#pragma unroll
    for (int it = 0; it < 4; ++it) {
      int e = (tid + it * 256) * 8;
      int row = e >> 7, col = e & 127;
      *(uint4*)(ob + e) = *(const uint4*)(xls + row * 136 + col);
    }
  }
}

extern "C" void kernel_launch(void* const* d_in, const int* in_sizes, int n_in,
                              void* d_out, int out_size, void* d_ws, size_t ws_size,
                              hipStream_t stream) {
  const void* x      = d_in[0];
  const void* Wqkv   = d_in[1];
  const void* Wproj  = d_in[2];
  const void* bproj  = d_in[3];
  const void* w1     = d_in[4];
  const void* b1     = d_in[5];
  const void* w2     = d_in[6];
  const void* hts    = d_in[7];
  const void* pps    = d_in[8];
  const void* ws1    = d_in[9];
  const void* ws2    = d_in[10];
  const int*  rel    = (const int*)d_in[11];
  const void* coords = d_in[12];
  char* ws  = (char*)d_ws;

  prep_transpose<<<256, 256, 0, stream>>>(Wqkv, Wproj, coords, ws);
  prep_table<<<225, 512, 0, stream>>>(coords, w1, b1, w2, hts, pps, ws1, ws2, ws);
  prep_gather<<<16, 256, 0, stream>>>(rel, ws);
  wattn_main<<<4096, 256, 0, stream>>>(x, ws, bproj, coords, d_out);
}